// Round 8
// baseline (575.926 us; speedup 1.0000x reference)
//
#include <hip/hip_runtime.h>
#include <cfloat>

// Problem constants (match reference)
constexpr int Bn = 1024, Ln = 1024, Vn = 20, Dn = 128;
constexpr int NJ = 2 * Vn;      // 40 output columns
constexpr int TB = 16;          // steps per resync block

// v mod 20 for 0 <= v <= ~4000 (magic multiply, exact in this range)
__device__ __forceinline__ int mod20(int v) { return v - 20 * ((v * 205) >> 12); }

// ---- DPP helpers: in-row (16-lane) butterfly max, pure VALU (proven R7) ----
template<int CTRL>
__device__ __forceinline__ float dpp_max(float v) {
  const int s = __builtin_amdgcn_update_dpp(0, __float_as_int(v), CTRL, 0xF, 0xF, false);
  return fmaxf(v, __int_as_float(s));
}
__device__ __forceinline__ float rowmax16(float v) {
  v = dpp_max<0xB1>(v);    // quad_perm xor1
  v = dpp_max<0x4E>(v);    // quad_perm xor2
  v = dpp_max<0x141>(v);   // row_half_mirror
  v = dpp_max<0x140>(v);   // row_mirror
  return v;
}

// inv mod 20 packed table: 5-bit entries for odd s, indexed by s>>1
constexpr unsigned long long INVT =
    (1ull << 0) | (7ull << 5) | (0ull << 10) | (3ull << 15) | (9ull << 20) |
    (11ull << 25) | (17ull << 30) | (0ull << 35) | (13ull << 40) | (19ull << 45);

__global__ __launch_bounds__(64, 1) void daf_chain(
    const float* __restrict__ x, const float* __restrict__ emb,
    const float* __restrict__ W, const float* __restrict__ bvec,
    float* __restrict__ out)
{
  __shared__ float Ws[Dn * NJ];                  // 20480 B: W row-major f32
  __shared__ float embd[Vn * Dn];                // 10240 B: emb rows f32
  __shared__ alignas(8) float ewd2[Vn * 64];     //  5120 B: EW distributed {lo,hi}/pos
  __shared__ alignas(16) double st64[Dn];        //  1024 B: f64 copy of f32 state
  __shared__ float nets40[64];                   //   256 B: resync share (padded)
  __shared__ alignas(16) unsigned char aidx[Ln]; //  1024 B: token index per step

  const int lane = threadIdx.x;
  const int batch = blockIdx.x;
  const int p   = lane & 15;          // position within row
  const int rB  = (lane >> 4) & 1;    // 0 = loc row, 1 = scale row
  const int pos = lane & 31;          // row-pair position (lanes 32..63 mirror)

  // resync column ownership (40 owner lanes)
  const bool own = (lane < Vn) || (lane >= 32 && lane < 32 + Vn);
  const int  jm  = (lane < 32) ? lane : (lane - 32 + Vn);
  const int  jc  = own ? jm : 0;

  // ---- Prologue: stage W, emb; extract token indices (coalesced float4) ----
  for (int i = lane; i < Dn * NJ; i += 64) Ws[i] = W[i];
  for (int i = lane; i < Vn * Dn; i += 64) embd[i] = emb[i];
  const float4* xb4 = (const float4*)(x + (size_t)batch * Ln * Vn);
  for (int i = lane; i < Ln * (Vn / 4); i += 64) {
    const float4 v = xb4[i];
    const int row = i / 5, cb = (i % 5) * 4;
    if (v.x > 0.5f) aidx[row] = (unsigned char)(cb + 0);
    if (v.y > 0.5f) aidx[row] = (unsigned char)(cb + 1);
    if (v.z > 0.5f) aidx[row] = (unsigned char)(cb + 2);
    if (v.w > 0.5f) aidx[row] = (unsigned char)(cb + 3);
  }
  __syncthreads();

  // ---- EW[k][j] = f64 dot(emb[k], W[:,j]) -> f32, distributed layout (R7) ----
  for (int e = lane; e < Vn * NJ; e += 64) {
    const int k = e / NJ, j = e - k * NJ;
    double acc = 0.0;
#pragma unroll 4
    for (int d = 0; d < Dn; ++d)
      acc = __builtin_fma((double)embd[k * Dn + d], (double)Ws[d * NJ + j], acc);
    int q, slot;
    if (j < 16)      { q = j;             slot = 0; }
    else if (j < 20) { q = j - 16;        slot = 1; }
    else if (j < 36) { q = 16 + (j - 20); slot = 0; }
    else             { q = 16 + (j - 36); slot = 1; }
    ewd2[k * 64 + q * 2 + slot] = (float)acc;
  }
  if ((pos & 15) >= 4)   // zero undefined hi slots so (-inf += 0) stays -inf
    for (int k = 0; k < Vn; ++k) ewd2[k * 64 + pos * 2 + 1] = 0.0f;
  __syncthreads();

  // ---- EW column into 40 named, pinned VGPRs (same f32 values as LDS) ----
  const float2* ew2 = (const float2*)ewd2;
#define ELOAD(k) float eL##k, eH##k; \
  { const float2 _e = ew2[(k) * 32 + pos]; eL##k = _e.x; eH##k = _e.y; } \
  asm volatile("" : "+v"(eL##k), "+v"(eH##k));
  ELOAD(0)  ELOAD(1)  ELOAD(2)  ELOAD(3)  ELOAD(4)
  ELOAD(5)  ELOAD(6)  ELOAD(7)  ELOAD(8)  ELOAD(9)
  ELOAD(10) ELOAD(11) ELOAD(12) ELOAD(13) ELOAD(14)
  ELOAD(15) ELOAD(16) ELOAD(17) ELOAD(18) ELOAD(19)

  // ---- init nets (distributed): exact f32 b (state 0) ----
  const int jlo = rB ? (20 + p) : p;
  float nlo = bvec[jlo];
  float nhi = (p < 4) ? bvec[jlo + 16] : -FLT_MAX;
  const double bj = (double)bvec[jc];

  float s32a = 0.0f, s32b = 0.0f;   // bit-exact f32 state walk (d=lane, lane+64)
  float* outb = out + (size_t)batch * Ln * Vn;
  const double2* st2 = (const double2*)st64;
  const float*   Wsc = Ws + jc;

  for (int tb = 0; tb < Ln / TB; ++tb) {
    // token prefetch: 16 tokens -> 4 SGPRs
    const uint4 tv = *(const uint4*)(aidx + tb * TB);
    const int tk0 = __builtin_amdgcn_readfirstlane((int)tv.x);
    const int tk1 = __builtin_amdgcn_readfirstlane((int)tv.y);
    const int tk2 = __builtin_amdgcn_readfirstlane((int)tv.z);
    const int tk3 = __builtin_amdgcn_readfirstlane((int)tv.w);

#pragma unroll
    for (int u = 0; u < TB; ++u) {
      const int t = tb * TB + u;
      const int tw = (u < 4) ? tk0 : (u < 8) ? tk1 : (u < 12) ? tk2 : tk3;
      const int as = (tw >> ((u & 3) * 8)) & 0xFF;   // 1 SALU extract

      // ---- argmax: proven fmax+4-DPP max, then ballot index extraction ----
      float m = fmaxf(nlo, nhi);
      m = rowmax16(m);
      const unsigned long long bLo = __ballot(nlo == m);
      const unsigned long long bHi = __ballot(nhi == m);
      const unsigned mLoc  = (unsigned)bLo & 0xFFFFu;          // loc j=0..15
      const unsigned mLocH = (unsigned)bHi & 0xFu;             // loc j=16..19
      const unsigned mScl  = (unsigned)(bLo >> 16) & 0xFFFFu;  // scale j=0..15
      const unsigned mSclH = (unsigned)(bHi >> 16) & 0xFu;     // scale j=16..19
      const int locI = mLoc ? (int)__builtin_ctz(mLoc) : 16 + (int)__builtin_ctz(mLocH);
      const int sclI = mScl ? (int)__builtin_ctz(mScl) : 16 + (int)__builtin_ctz(mSclH);

      // oidx = (inv20(scale) * ((a - loc) mod 20)) mod 20  (scalar chain)
      int r = as - locI; r += (r >> 31) & Vn;
      const int inv = (sclI & 1) ? (int)((INVT >> ((sclI >> 1) * 5)) & 31ull) : 0;
      const int oidx = mod20(inv * r);

      // one-hot output row (80 B store, fire-and-forget)
      if (lane < Vn) outb[(size_t)t * Vn + lane] = (lane == oidx) ? 1.0f : 0.0f;

      // exact f32 state walk (off-chain: only consumed by resync)
      s32a += embd[oidx * Dn + lane];
      s32b += embd[oidx * Dn + lane + 64];

      if (u != TB - 1) {
        // VGPR copy of uniform oidx -> divergent-typed bools -> v_cndmask tree
        int ov; asm("v_mov_b32 %0, %1" : "=v"(ov) : "s"(oidx));
        const bool b0 = ov & 1, b1 = ov & 2, b2 = ov & 4, b3 = ov & 8, b4 = ov & 16;
        // level 0 (10+10 selects)
        const float sL0 = b0 ? eL1  : eL0,  sH0 = b0 ? eH1  : eH0;
        const float sL1 = b0 ? eL3  : eL2,  sH1 = b0 ? eH3  : eH2;
        const float sL2 = b0 ? eL5  : eL4,  sH2 = b0 ? eH5  : eH4;
        const float sL3 = b0 ? eL7  : eL6,  sH3 = b0 ? eH7  : eH6;
        const float sL4 = b0 ? eL9  : eL8,  sH4 = b0 ? eH9  : eH8;
        const float sL5 = b0 ? eL11 : eL10, sH5 = b0 ? eH11 : eH10;
        const float sL6 = b0 ? eL13 : eL12, sH6 = b0 ? eH13 : eH12;
        const float sL7 = b0 ? eL15 : eL14, sH7 = b0 ? eH15 : eH14;
        const float sL8 = b0 ? eL17 : eL16, sH8 = b0 ? eH17 : eH16;
        const float sL9 = b0 ? eL19 : eL18, sH9 = b0 ? eH19 : eH18;
        // level 1 (5+5)
        const float uL0 = b1 ? sL1 : sL0, uH0 = b1 ? sH1 : sH0;
        const float uL1 = b1 ? sL3 : sL2, uH1 = b1 ? sH3 : sH2;
        const float uL2 = b1 ? sL5 : sL4, uH2 = b1 ? sH5 : sH4;
        const float uL3 = b1 ? sL7 : sL6, uH3 = b1 ? sH7 : sH6;
        const float uL4 = b1 ? sL9 : sL8, uH4 = b1 ? sH9 : sH8;
        // level 2 (2+2)
        const float vL0 = b2 ? uL1 : uL0, vH0 = b2 ? uH1 : uH0;
        const float vL1 = b2 ? uL3 : uL2, vH1 = b2 ? uH3 : uH2;
        // level 3 (1+1)
        const float wL0 = b3 ? vL1 : vL0, wH0 = b3 ? vH1 : vH0;
        // level 4 (1+1): idx 16..19 live in uL4/uH4
        const float resL = b4 ? uL4 : wL0, resH = b4 ? uH4 : wH0;
        nlo += resL;
        nhi += resH;
      }
    }

    if (tb != Ln / TB - 1) {
      // ---- Resync (byte-for-byte R7, proven): f32(b + f64 dot of f32 state) ----
      st64[lane]      = (double)s32a;
      st64[lane + 64] = (double)s32b;
      __syncthreads();
      double a0 = 0.0, a1 = 0.0, a2 = 0.0, a3 = 0.0;
#pragma unroll
      for (int d = 0; d < Dn; d += 4) {
        const double2 sA = st2[d >> 1];
        const double2 sB = st2[(d >> 1) + 1];
        a0 = __builtin_fma(sA.x, (double)Wsc[(d + 0) * NJ], a0);
        a1 = __builtin_fma(sA.y, (double)Wsc[(d + 1) * NJ], a1);
        a2 = __builtin_fma(sB.x, (double)Wsc[(d + 2) * NJ], a2);
        a3 = __builtin_fma(sB.y, (double)Wsc[(d + 3) * NJ], a3);
      }
      if (own) nets40[jm] = (float)(((a0 + a1) + (a2 + a3)) + bj);
      __syncthreads();
      nlo = nets40[rB * 20 + p];
      nhi = (p < 4) ? nets40[rB * 20 + 16 + p] : -FLT_MAX;
    }
  }
}

extern "C" void kernel_launch(void* const* d_in, const int* in_sizes, int n_in,
                              void* d_out, int out_size, void* d_ws, size_t ws_size,
                              hipStream_t stream) {
  const float* x   = (const float*)d_in[0];
  const float* emb = (const float*)d_in[1];
  const float* W   = (const float*)d_in[2];
  const float* b   = (const float*)d_in[3];
  float* out = (float*)d_out;
  hipLaunchKernelGGL(daf_chain, dim3(Bn), dim3(64), 0, stream,
                     x, emb, W, b, out);
}

// Round 9
// 329.216 us; speedup vs baseline: 1.7494x; 1.7494x over previous
//
#include <hip/hip_runtime.h>
#include <cfloat>

// Problem constants (match reference)
constexpr int Bn = 1024, Ln = 1024, Vn = 20, Dn = 128;
constexpr int NJ = 2 * Vn;      // 40 output columns
constexpr int TB = 16;          // steps per resync block

// v mod 20 for 0 <= v <= ~4000 (magic multiply, exact in this range)
__device__ __forceinline__ int mod20(int v) { return v - 20 * ((v * 205) >> 12); }

// ---- DPP helpers: in-row (16-lane) butterfly max, pure VALU (proven R7) ----
template<int CTRL>
__device__ __forceinline__ float dpp_max(float v) {
  const int s = __builtin_amdgcn_update_dpp(0, __float_as_int(v), CTRL, 0xF, 0xF, false);
  return fmaxf(v, __int_as_float(s));
}
__device__ __forceinline__ float rowmax16(float v) {
  v = dpp_max<0xB1>(v);    // quad_perm xor1
  v = dpp_max<0x4E>(v);    // quad_perm xor2
  v = dpp_max<0x141>(v);   // row_half_mirror
  v = dpp_max<0x140>(v);   // row_mirror
  return v;
}

// inv mod 20 packed table: 5-bit entries for odd s, indexed by s>>1
constexpr unsigned long long INVT =
    (1ull << 0) | (7ull << 5) | (0ull << 10) | (3ull << 15) | (9ull << 20) |
    (11ull << 25) | (17ull << 30) | (0ull << 35) | (13ull << 40) | (19ull << 45);

__global__ __launch_bounds__(64, 1) void daf_chain(
    const float* __restrict__ x, const float* __restrict__ emb,
    const float* __restrict__ W, const float* __restrict__ bvec,
    float* __restrict__ out)
{
  __shared__ float Ws[Dn * NJ];                  // 20480 B: W row-major f32
  __shared__ float embd[Vn * Dn];                // 10240 B: emb rows f32
  __shared__ alignas(8) float ewd2[Vn * 64];     //  5120 B: EW distributed {lo,hi}/pos
  __shared__ alignas(16) double st64[Dn];        //  1024 B: f64 copy of f32 state
  __shared__ float nets40[64];                   //   256 B: resync share (padded)
  __shared__ alignas(16) unsigned char aidx[Ln]; //  1024 B: token index per step

  const int lane = threadIdx.x;
  const int batch = blockIdx.x;
  const int p   = lane & 15;          // position within row
  const int rB  = (lane >> 4) & 1;    // 0 = loc row, 1 = scale row
  const int pos = lane & 31;          // row-pair position (lanes 32..63 mirror)

  // resync column ownership (40 owner lanes)
  const bool own = (lane < Vn) || (lane >= 32 && lane < 32 + Vn);
  const int  jm  = (lane < 32) ? lane : (lane - 32 + Vn);
  const int  jc  = own ? jm : 0;

  // ---- Prologue: stage W, emb; extract token indices (coalesced float4) ----
  // Single-wave block: LDS ops complete in-order within the wave -> no barriers.
  for (int i = lane; i < Dn * NJ; i += 64) Ws[i] = W[i];
  for (int i = lane; i < Vn * Dn; i += 64) embd[i] = emb[i];
  const float4* xb4 = (const float4*)(x + (size_t)batch * Ln * Vn);
  for (int i = lane; i < Ln * (Vn / 4); i += 64) {
    const float4 v = xb4[i];
    const int row = i / 5, cb = (i % 5) * 4;
    if (v.x > 0.5f) aidx[row] = (unsigned char)(cb + 0);
    if (v.y > 0.5f) aidx[row] = (unsigned char)(cb + 1);
    if (v.z > 0.5f) aidx[row] = (unsigned char)(cb + 2);
    if (v.w > 0.5f) aidx[row] = (unsigned char)(cb + 3);
  }

  // ---- EW[k][j] = f64 dot(emb[k], W[:,j]) -> f32, distributed layout (R7) ----
  for (int e = lane; e < Vn * NJ; e += 64) {
    const int k = e / NJ, j = e - k * NJ;
    double acc = 0.0;
#pragma unroll 4
    for (int d = 0; d < Dn; ++d)
      acc = __builtin_fma((double)embd[k * Dn + d], (double)Ws[d * NJ + j], acc);
    int q, slot;
    if (j < 16)      { q = j;             slot = 0; }
    else if (j < 20) { q = j - 16;        slot = 1; }
    else if (j < 36) { q = 16 + (j - 20); slot = 0; }
    else             { q = 16 + (j - 36); slot = 1; }
    ewd2[k * 64 + q * 2 + slot] = (float)acc;
  }
  if ((pos & 15) >= 4)   // zero undefined hi slots so (-FLT_MAX += 0) stays put
    for (int k = 0; k < Vn; ++k) ewd2[k * 64 + pos * 2 + 1] = 0.0f;

  // ---- init nets (distributed): exact f32 b (state 0) ----
  const int jlo = rB ? (20 + p) : p;
  float nlo = bvec[jlo];
  float nhi = (p < 4) ? bvec[jlo + 16] : -FLT_MAX;
  const double bj = (double)bvec[jc];

  float s32a = 0.0f, s32b = 0.0f;   // bit-exact f32 state walk (d=lane, lane+64)
  float* outb = out + (size_t)batch * Ln * Vn;
  const double2* st2 = (const double2*)st64;
  const float*   Wsc = Ws + jc;
  const float2*  ew2 = (const float2*)ewd2;
  const int vpos8 = pos * 8;        // per-lane EW byte offset (hoisted)

  for (int tb = 0; tb < Ln / TB; ++tb) {
    // token prefetch: 16 tokens -> 4 SGPRs (one broadcast b128 read)
    const uint4 tv = *(const uint4*)(aidx + tb * TB);
    const int tk0 = __builtin_amdgcn_readfirstlane((int)tv.x);
    const int tk1 = __builtin_amdgcn_readfirstlane((int)tv.y);
    const int tk2 = __builtin_amdgcn_readfirstlane((int)tv.z);
    const int tk3 = __builtin_amdgcn_readfirstlane((int)tv.w);

    unsigned long long q0 = 0ull, q1 = 0ull;   // 16 x 5-bit oidx, SGPR-packed

#pragma unroll
    for (int u = 0; u < TB; ++u) {
      const int tw = (u < 4) ? tk0 : (u < 8) ? tk1 : (u < 12) ? tk2 : tk3;
      const int as = (tw >> ((u & 3) * 8)) & 0xFF;   // SALU extract

      // ---- argmax: proven fmax + 4-DPP f32 max; ballot index extraction ----
      float m = fmaxf(nlo, nhi);
      m = rowmax16(m);
      const unsigned long long bLo = __ballot(nlo == m);
      const unsigned long long bHi = __ballot(nhi == m);
      const unsigned mLoc  = (unsigned)bLo & 0xFFFFu;          // loc j=0..15
      const unsigned mLocH = (unsigned)bHi & 0xFu;             // loc j=16..19
      const unsigned mScl  = (unsigned)(bLo >> 16) & 0xFFFFu;  // scale j=0..15
      const unsigned mSclH = (unsigned)(bHi >> 16) & 0xFu;     // scale j=16..19
      const int locI = mLoc ? (int)__builtin_ctz(mLoc) : 16 + (int)__builtin_ctz(mLocH);
      const int sclI = mScl ? (int)__builtin_ctz(mScl) : 16 + (int)__builtin_ctz(mSclH);

      // oidx = (inv20(scale) * ((a - loc) mod 20)) mod 20  (scalar chain)
      int r = as - locI; r += (r >> 31) & Vn;
      const int inv = (sclI & 1) ? (int)((INVT >> ((sclI >> 1) * 5)) & 31ull) : 0;
      const int oidx = mod20(inv * r);

      // EW fetch + net update first (the serial chain); bookkeeping after.
      if (u != TB - 1) {
        const float2 e = ew2[oidx * 32 + pos];   // one ds_read_b64, sole LDS op
        nlo += e.x; nhi += e.y;
      }

      // pack oidx (SALU, off-chain)
      if (u < 8) q0 |= (unsigned long long)(unsigned)oidx << (5 * u);
      else       q1 |= (unsigned long long)(unsigned)oidx << (5 * (u - 8));
    }

    // ---- batched one-hot writeback: 320 floats, fully coalesced ----
    {
      const int rl = lane >> 2;                 // which step of the block
      const unsigned long long w = (rl < 8) ? q0 : q1;
      const int od = (int)((w >> (5 * (rl & 7))) & 31ull);
      float* ob = outb + (size_t)tb * (TB * Vn) + lane * 5;
      const int c0 = (lane & 3) * 5;
#pragma unroll
      for (int c = 0; c < 5; ++c)
        ob[c] = (c0 + c == od) ? 1.0f : 0.0f;
    }

    if (tb != Ln / TB - 1) {
      // ---- deferred exact f32 state walk: same order/values as per-step ----
#pragma unroll
      for (int u = 0; u < TB; ++u) {
        const int ou = (int)(((u < 8) ? (q0 >> (5 * u)) : (q1 >> (5 * (u - 8)))) & 31ull);
        s32a += embd[ou * Dn + lane];
        s32b += embd[ou * Dn + lane + 64];
      }
      // ---- Resync (proven numerics): nets = f32(b + f64 dot of f32 state) ----
      st64[lane]      = (double)s32a;
      st64[lane + 64] = (double)s32b;
      double a0 = 0.0, a1 = 0.0, a2 = 0.0, a3 = 0.0;
#pragma unroll
      for (int d = 0; d < Dn; d += 4) {
        const double2 sA = st2[d >> 1];
        const double2 sB = st2[(d >> 1) + 1];
        a0 = __builtin_fma(sA.x, (double)Wsc[(d + 0) * NJ], a0);
        a1 = __builtin_fma(sA.y, (double)Wsc[(d + 1) * NJ], a1);
        a2 = __builtin_fma(sB.x, (double)Wsc[(d + 2) * NJ], a2);
        a3 = __builtin_fma(sB.y, (double)Wsc[(d + 3) * NJ], a3);
      }
      if (own) nets40[jm] = (float)(((a0 + a1) + (a2 + a3)) + bj);
      nlo = nets40[rB * 20 + p];
      nhi = (p < 4) ? nets40[rB * 20 + 16 + p] : -FLT_MAX;
    }
  }
}

extern "C" void kernel_launch(void* const* d_in, const int* in_sizes, int n_in,
                              void* d_out, int out_size, void* d_ws, size_t ws_size,
                              hipStream_t stream) {
  const float* x   = (const float*)d_in[0];
  const float* emb = (const float*)d_in[1];
  const float* W   = (const float*)d_in[2];
  const float* b   = (const float*)d_in[3];
  float* out = (float*)d_out;
  hipLaunchKernelGGL(daf_chain, dim3(Bn), dim3(64), 0, stream,
                     x, emb, W, b, out);
}